// Round 8
// baseline (186.408 us; speedup 1.0000x reference)
//
#include <hip/hip_runtime.h>
#include <math.h>

// Problem constants: bases [1,4,136,200] f32, box_feat [N,789] f32
// (col0 = image idx, 1:5 = box, 5: = 4*14*14 coeffs), out [N,544,800] f32.
#define OUTD 56
#define COD  14
#define BH   136
#define BW   200
#define IMGH 544
#define IMGW 800
#define BB   4
#define BFS  789    // 5 + 4*14*14
#define GRP  16     // image rows per block; IMGH/GRP = 34
#define W4   (IMGW / 4)          // 200 float4 per row
#define ELEMS (GRP * W4)         // 3200 float4 per block

// Native vector type: __builtin_nontemporal_store requires a clang vector,
// not HIP's HIP_vector_type class.
typedef float vfloat4 __attribute__((ext_vector_type(4)));

// ---------------------------------------------------------------------------
// Heavy mask eval at mask pixel (y, x) for one roi:
// roi_align(bases, aligned=True, sampling_ratio=1) + 14->56 bilinear coeff
// upsample + softmax over 4 bases + dot + sigmoid.
// ---------------------------------------------------------------------------
__device__ __forceinline__ float mask_value(
    const float* __restrict__ feat, const float* __restrict__ top,
    float sx0, float sy0, float bwv, float bhv, int y, int x) {
  const float ysv = sy0 + ((float)y + 0.5f) * bhv;
  const float xsv = sx0 + ((float)x + 0.5f) * bwv;
  const float valid =
      (ysv >= -1.0f && ysv <= (float)BH && xsv >= -1.0f && xsv <= (float)BW)
          ? 1.0f : 0.0f;
  const float yc = fminf(fmaxf(ysv, 0.0f), (float)(BH - 1));
  const float xc = fminf(fmaxf(xsv, 0.0f), (float)(BW - 1));
  int yl = (int)floorf(yc); yl = yl > (BH - 2) ? (BH - 2) : yl;  // yc >= 0
  int xl = (int)floorf(xc); xl = xl > (BW - 2) ? (BW - 2) : xl;
  const float ly = yc - (float)yl, hy = 1.0f - ly;
  const float lx = xc - (float)xl, hx = 1.0f - lx;
  const float w00 = hy * hx, w01 = hy * lx, w10 = ly * hx, w11 = ly * lx;

  float cyf = fminf(fmaxf(((float)y + 0.5f) * 0.25f - 0.5f, 0.0f), (float)(COD - 1));
  float cxf = fminf(fmaxf(((float)x + 0.5f) * 0.25f - 0.5f, 0.0f), (float)(COD - 1));
  int cyl = (int)floorf(cyf); cyl = cyl > (COD - 2) ? (COD - 2) : cyl;
  int cxl = (int)floorf(cxf); cxl = cxl > (COD - 2) ? (COD - 2) : cxl;
  const float cly = cyf - (float)cyl, chy = 1.0f - cly;
  const float clx = cxf - (float)cxl, chx = 1.0f - clx;
  const float cw00 = chy * chx, cw01 = chy * clx, cw10 = cly * chx, cw11 = cly * clx;

  float rvals[BB], cvals[BB];
#pragma unroll
  for (int b = 0; b < BB; ++b) {
    const float* fb = feat + b * BH * BW;
    const float r = w00 * fb[yl * BW + xl]       + w01 * fb[yl * BW + xl + 1] +
                    w10 * fb[(yl + 1) * BW + xl] + w11 * fb[(yl + 1) * BW + xl + 1];
    rvals[b] = r * valid;
    const float* tb = top + b * COD * COD;
    cvals[b] = cw00 * tb[cyl * COD + cxl]       + cw01 * tb[cyl * COD + cxl + 1] +
               cw10 * tb[(cyl + 1) * COD + cxl] + cw11 * tb[(cyl + 1) * COD + cxl + 1];
  }

  const float mx = fmaxf(fmaxf(cvals[0], cvals[1]), fmaxf(cvals[2], cvals[3]));
  float e[BB], s = 0.0f;
#pragma unroll
  for (int b = 0; b < BB; ++b) { e[b] = __expf(cvals[b] - mx); s += e[b]; }
  const float inv = 1.0f / s;
  float dot = 0.0f;
#pragma unroll
  for (int b = 0; b < BB; ++b) dot += rvals[b] * (e[b] * inv);
  return 1.0f / (1.0f + __expf(-dot));
}

// ---------------------------------------------------------------------------
// Single fused kernel: 16 output rows per block (grid = 34 x N, 3400 blocks).
// Zero groups: unrolled nontemporal float4 zero-store loop (write-once data,
// nt skips L2 allocation). Interior groups: compute only the needed mask rows
// (~12-24 of 56) into LDS, then flattened predicated bilinear paste with
// nontemporal stores; all 256 threads store 12.5 float4 each, coalesced.
// ---------------------------------------------------------------------------
__global__ __launch_bounds__(256) void fused_paste(
    const float* __restrict__ bases,
    const float* __restrict__ box_feat,
    vfloat4* __restrict__ out) {
  const int n  = blockIdx.y;
  const int hs = (int)blockIdx.x * GRP;
  const int tid = threadIdx.x;

  const float* bf = box_feat + (size_t)n * BFS;
  const float x0 = bf[1], y0 = bf[2], x1 = bf[3], y1 = bf[4];

  vfloat4* obase = out + ((size_t)n * IMGH + hs) * W4;

  const float sy = (float)OUTD / (y1 - y0);
  const float cyc_ = (0.5f - y0) * sy - 0.5f;      // fy(h) = h*sy + cyc_
  const float fy_first = (float)hs * sy + cyc_;
  const float fy_last  = (float)(hs + GRP - 1) * sy + cyc_;

  // Group entirely outside vertical tent support -> pure zero-store loop.
  if (!(fy_last > -1.0f && fy_first < (float)OUTD)) {
    const vfloat4 z = (vfloat4)(0.0f);
#pragma unroll 2
    for (int idx = tid; idx < ELEMS; idx += 256)
      __builtin_nontemporal_store(z, &obase[idx]);
    return;
  }

  // ---- compute the needed mask rows into LDS ----
  __shared__ float m[OUTD * OUTD];
  {
    const int lo = max(0, (int)floorf(fy_first));
    const int hi = min(OUTD - 1, (int)floorf(fy_last) + 1);
    const int cnt = (hi - lo + 1) * OUTD;

    const int bidx = (int)bf[0];
    const float sx0 = x0 * 0.25f - 0.5f;
    const float sy0 = y0 * 0.25f - 0.5f;
    const float bwv = (x1 - x0) * 0.25f * (1.0f / OUTD);
    const float bhv = (y1 - y0) * 0.25f * (1.0f / OUTD);
    const float* feat = bases + (size_t)bidx * BB * BH * BW;
    const float* top  = bf + 5;

    for (int i = tid; i < cnt; i += 256) {
      const int rr = i / OUTD;
      const int x = i - rr * OUTD;
      const int r = lo + rr;
      m[r * OUTD + x] = mask_value(feat, top, sx0, sy0, bwv, bhv, r, x);
    }
  }
  __syncthreads();

  const float invw = (float)OUTD / (x1 - x0);
  const float cxc = (0.5f - x0) * invw - 0.5f;     // fx(q) = q*invw + cxc

  // Flattened loop over GRP*W4 elements; step 256 = 1*W4 + 56.
  int row = tid / W4;
  int col = tid - row * W4;
  for (int idx = tid; idx < ELEMS; idx += 256) {
    const float fy = (float)(hs + row) * sy + cyc_;
    vfloat4 o = (vfloat4)(0.0f);
    if (fy > -1.0f && fy < (float)OUTD) {
      const int ml = (int)floorf(fy);              // -1 .. 55
      float wy1 = fy - (float)ml;
      float wy0 = 1.0f - wy1;
      const int r0 = ml < 0 ? 0 : ml;
      const int r1 = (ml + 1 > OUTD - 1) ? (OUTD - 1) : (ml + 1);
      if (ml < 0) wy0 = 0.0f;
      if (ml + 1 > OUTD - 1) wy1 = 0.0f;
      const float* row0 = &m[r0 * OUTD];
      const float* row1 = &m[r1 * OUTD];
#pragma unroll
      for (int i = 0; i < 4; ++i) {
        const float q = (float)(col * 4 + i);
        const float fx = fmaf(q, invw, cxc);
        float v = 0.0f;
        if (fx > -1.0f && fx < (float)OUTD) {
          const int xl = (int)floorf(fx);
          float wx1 = fx - (float)xl;
          float wx0 = 1.0f - wx1;
          const int xls = xl < 0 ? 0 : xl;
          const int xhs = (xl + 1 > OUTD - 1) ? (OUTD - 1) : (xl + 1);
          if (xl < 0) wx0 = 0.0f;
          if (xl + 1 > OUTD - 1) wx1 = 0.0f;
          v = wy0 * (wx0 * row0[xls] + wx1 * row0[xhs]) +
              wy1 * (wx0 * row1[xls] + wx1 * row1[xhs]);
        }
        o[i] = v;
      }
    }
    __builtin_nontemporal_store(o, &obase[row * W4 + col]);
    // advance flat index by 256 = W4 + 56
    row += 1;
    col += 56;
    if (col >= W4) { col -= W4; row += 1; }
  }
}

extern "C" void kernel_launch(void* const* d_in, const int* in_sizes, int n_in,
                              void* d_out, int out_size, void* d_ws, size_t ws_size,
                              hipStream_t stream) {
  const float* bases    = (const float*)d_in[0];
  const float* box_feat = (const float*)d_in[1];
  const int N = in_sizes[1] / BFS;

  dim3 grid(IMGH / GRP, N);
  fused_paste<<<grid, 256, 0, stream>>>(bases, box_feat, (vfloat4*)d_out);
}